// Round 9
// baseline (39.050 us; speedup 1.0000x reference)
//
#include <hip/hip_runtime.h>

// InvariantPolynomial: out = sum_e xl[oi[e]] * xr[e] * f(|pos_e|)
// f depends only on d=|pos| (sh[:,:1]==1); 2048-entry linear LUT over [0,5].
//
// R9 = R8 with the compile fix: __builtin_nontemporal_load needs clang
// ext_vector_type pointers, not HIP_vector_type (struct) pointers.
//  - NT loads on pos/xr/oi (read-once streams must not evict xl from L2;
//    xl = 500KB with 256x line reuse -- keeping it L2-resident is the win)
//  - EPT=4 -> 1954 blocks -> ~30 waves/CU (was 15) for latency hiding
//  - oi issued first so the oi->xl chain starts ASAP
// ws layout: [0,8KB) float LUT.

#define TN    2048
#define DMAXF 5.0f
#define TPB   256
#define EPT   4
#define TILE  (TPB * EPT)   // 1024 edges per block

typedef float fx4 __attribute__((ext_vector_type(4)));
typedef int   ix4 __attribute__((ext_vector_type(4)));

// 1/sqrt(E[silu(z)^2]); matched reference exactly (absmax 0.0, R1-R7)
__device__ __constant__ float kSiluCst = 1.6765581f;

__global__ __launch_bounds__(256) void build_lut_kernel(
    const float* __restrict__ W1, const float* __restrict__ W2,
    float* __restrict__ table, float* __restrict__ out)
{
    if (blockIdx.x == 0 && threadIdx.x == 0) out[0] = 0.0f;  // replay-safe reset

    // 32 lanes per LUT entry: lane k in [0,30) computes hidden unit k.
    int t = blockIdx.x * 256 + threadIdx.x;
    int entry = t >> 5;
    int k = t & 31;
    int kk = (k < 30) ? k : 29;

    float d  = (float)entry * (DMAXF / (float)TN);
    float t6 = 6.0f * d;                      // gaussian centers at t6 = 1..20
    const float w1scale = 1.0f / (1.12f * sqrtf(20.0f));

    float a = 0.0f;
    #pragma unroll
    for (int j = 0; j < 20; ++j) {
        float df = t6 - (float)(j + 1);
        float e  = __expf(-df * df);
        a = fmaf(e * w1scale, W1[j * 30 + kk], a);
    }
    float s = a / (1.0f + __expf(-a));        // silu

    float w2s = 0.0f;
    #pragma unroll
    for (int c = 0; c < 5; ++c) w2s += W2[kk * 5 + c];

    float contrib = (k < 30) ? s * w2s * (kSiluCst / sqrtf(30.0f)) : 0.0f;

    #pragma unroll
    for (int m = 16; m > 0; m >>= 1) contrib += __shfl_xor(contrib, m, 32);

    if (k == 0 && entry < TN) table[entry] = contrib;
}

__global__ __launch_bounds__(TPB) void edge_sum_kernel(
    const float* __restrict__ pos, const float* __restrict__ xr,
    const float* __restrict__ xl, const int* __restrict__ oi,
    const float* __restrict__ table, float* __restrict__ out, int E)
{
    __shared__ float lut[TN];
    __shared__ double swv[TPB / 64];

    const int  tid   = threadIdx.x;
    const long tile0 = (long)blockIdx.x * TILE;
    const int  rem   = (int)min((long)TILE, (long)E - tile0);
    const int  e0    = tid * EPT;
    const bool full  = (e0 + EPT <= rem);

    // ---- issue read-once streams with NT loads (don't pollute L2) ----
    // oi first: the oi->xl dependent chain is the long pole.
    ix4 O; fx4 X, P0, P1, P2;
    if (full) {
        const long g0 = tile0 + e0;
        O  = __builtin_nontemporal_load((const ix4*)(oi + g0));
        X  = __builtin_nontemporal_load((const fx4*)(xr + g0));
        const fx4* p4 = (const fx4*)(pos + g0 * 3);
        P0 = __builtin_nontemporal_load(p4 + 0);
        P1 = __builtin_nontemporal_load(p4 + 1);
        P2 = __builtin_nontemporal_load(p4 + 2);
    }

    {   // stage 8KB LUT (normal loads: table is L2-hot and shared by all blocks)
        const float4* t4 = (const float4*)table;
        float4* l4 = (float4*)lut;
        l4[tid]       = t4[tid];
        l4[tid + TPB] = t4[tid + TPB];
    }
    __syncthreads();

    const float scale = (float)TN / DMAXF;
    const float umax  = (float)(TN - 1) - 1e-3f;
    double acc = 0.0;

    if (full) {
        // xl gathers: normal loads, xl should now stay L2-resident
        float xlv[EPT];
        xlv[0] = xl[O.x]; xlv[1] = xl[O.y]; xlv[2] = xl[O.z]; xlv[3] = xl[O.w];

        float px[EPT] = {P0.x, P0.w, P1.z, P2.y};
        float py[EPT] = {P0.y, P1.x, P1.w, P2.z};
        float pz[EPT] = {P0.z, P1.y, P2.x, P2.w};
        float xrv[EPT] = {X.x, X.y, X.z, X.w};

        float fsum = 0.0f;
        #pragma unroll
        for (int j = 0; j < EPT; ++j) {
            float d  = sqrtf(fmaf(px[j], px[j], fmaf(py[j], py[j], pz[j] * pz[j])));
            float u  = fminf(d * scale, umax);
            int   i0 = (int)u;
            float fr = u - (float)i0;
            float f  = fmaf(fr, lut[i0 + 1] - lut[i0], lut[i0]);
            fsum = fmaf(f * xrv[j], xlv[j], fsum);
        }
        acc = (double)fsum;
    } else if (e0 < rem) {
        // guarded scalar tail (last block only)
        float fsum = 0.0f;
        for (int j = 0; j < EPT && e0 + j < rem; ++j) {
            long  ge = tile0 + e0 + j;
            float x = pos[3 * ge], y = pos[3 * ge + 1], z = pos[3 * ge + 2];
            float d  = sqrtf(fmaf(x, x, fmaf(y, y, z * z)));
            float u  = fminf(d * scale, umax);
            int   i0 = (int)u;
            float fr = u - (float)i0;
            float f  = fmaf(fr, lut[i0 + 1] - lut[i0], lut[i0]);
            fsum = fmaf(f * xr[ge], xl[oi[ge]], fsum);
        }
        acc = (double)fsum;
    }

    // deterministic block reduction (wave shfl + LDS across 4 waves)
    #pragma unroll
    for (int off = 32; off > 0; off >>= 1) acc += __shfl_down(acc, off);
    int lane = tid & 63, wv = tid >> 6;
    if (lane == 0) swv[wv] = acc;
    __syncthreads();
    if (tid == 0) {
        double bsum = (swv[0] + swv[1]) + (swv[2] + swv[3]);
        atomicAdd(out, (float)bsum);   // ~1954 atomics to one line: negligible
    }
}

extern "C" void kernel_launch(void* const* d_in, const int* in_sizes, int n_in,
                              void* d_out, int out_size, void* d_ws, size_t ws_size,
                              hipStream_t stream) {
    const float* pos = (const float*)d_in[0];   // [E,3]
    const float* xr  = (const float*)d_in[1];   // [E,1]
    const float* xl  = (const float*)d_in[2];   // [N,1]
    const float* W1  = (const float*)d_in[3];   // [20,30]
    const float* W2  = (const float*)d_in[4];   // [30,5]
    const int*   oi  = (const int*)d_in[5];     // [E]
    float* out = (float*)d_out;

    int E = in_sizes[1];
    int nblk = (E + TILE - 1) / TILE;           // 1954 for E=2M

    float* table = (float*)d_ws;

    hipLaunchKernelGGL(build_lut_kernel, dim3((TN * 32) / 256), dim3(256), 0, stream,
                       W1, W2, table, out);
    hipLaunchKernelGGL(edge_sum_kernel, dim3(nblk), dim3(TPB), 0, stream,
                       pos, xr, xl, oi, table, out, E);
}